// Round 12
// baseline (252.268 us; speedup 1.0000x reference)
//
#include <hip/hip_runtime.h>

// SegmentedAttention round 21 = revert to r19 proj (measured best: proj
// 61us, total 243.4) + kproj-first dispatch order.
// r20 post-mortem: 64x128 kproj split REGRESSED (69us): halved the
// mfma-per-LDS-read ratio, doubled B re-reads (FETCH 50->57MB), conflicts
// 8.4->11.5M. Lesson: with all blocks co-resident, kernel time = slowest
// block's duration; smaller tiles only degrade per-block efficiency.
// r21: kproj back to 128x128/BK=32/[.][40] (r19 config), placed at block
// IDs [0,256) so the 3x-FLOP blocks are dispatched first; QV at [256,768).
// proj floor ~61us is structural (barrier-lockstep k-loop); breaking it
// needs a gload_lds+swizzle rewrite (multi-round risk, deferred).
// ws (MB): kb16@0(8) qb16@8(8) vb16@16(8) vt16@24(8) xh@32(8,=fusedb)
//   xl@40(8) Wqt@48(2) Wvt@50(2) Wot@52(2) Wkh@54(2) Wkl@56(2) Wgt@58(1)
//   norms2@59(1) gk@60(1) gvt@61(1) -> 62MB

constexpr int SEQ    = 2048;
constexpr int DMODEL = 1024;
constexpr int NH     = 16;
constexpr int DHEAD  = 64;
constexpr int BHT    = 32;
constexpr int NG     = 204;
constexpr int NGPAD  = 256;
constexpr float LNEPS = 1e-5f;

typedef __attribute__((ext_vector_type(8))) short short8;
typedef __attribute__((ext_vector_type(4))) short short4v;
typedef __attribute__((ext_vector_type(4))) float f32x4;

__device__ __forceinline__ unsigned short f2bf(float f) {
    unsigned int u = __float_as_uint(f);
    u += 0x7FFFu + ((u >> 16) & 1u);
    return (unsigned short)(u >> 16);
}
__device__ __forceinline__ float bf2f(unsigned short b) {
    return __uint_as_float(((unsigned int)b) << 16);
}

// ---------------------------------------------------------------------------
// prep: blocks [0,2048): x hilo split; [2048,3072): weight transposes;
// block 3072: Wg^T bf16.
// ---------------------------------------------------------------------------
__global__ __launch_bounds__(256)
void prep_k(const float* __restrict__ x,
            const float* __restrict__ Wq, const float* __restrict__ Wv,
            const float* __restrict__ Wo, const float* __restrict__ Wk,
            const float* __restrict__ Wg,
            unsigned short* __restrict__ xh, unsigned short* __restrict__ xl,
            unsigned short* __restrict__ Wqt, unsigned short* __restrict__ Wvt,
            unsigned short* __restrict__ Wot, unsigned short* __restrict__ Wkh,
            unsigned short* __restrict__ Wkl, unsigned short* __restrict__ Wgt)
{
    const int bid = blockIdx.x;
    const int tid = threadIdx.x;

    if (bid < 2048) {
        int i = (bid * 256 + tid) << 3;
        short8 h, l;
#pragma unroll
        for (int j = 0; j < 8; ++j) {
            float v = x[i + j];
            unsigned short hb = f2bf(v);
            h[j] = (short)hb;
            l[j] = (short)f2bf(v - bf2f(hb));
        }
        *(short8*)(xh + i) = h;
        *(short8*)(xl + i) = l;
        return;
    }
    if (bid == 3072) {
#pragma unroll
        for (int i = 0; i < 32; ++i) {
            int o = tid * 32 + i;
            int dg = o >> 7, jj = o & 127;
            Wgt[o] = f2bf(Wg[jj * 64 + dg]);
        }
        return;
    }

    __shared__ float tile[64][68];
    const int sub = bid - 2048;
    const int which = sub >> 8;             // 0:Wq 1:Wv 2:Wo 3:Wk
    const int b = sub & 255;
    const int n0 = (b & 15) * 64, k0 = (b >> 4) * 64;
    const float* W = (which == 0) ? Wq : (which == 1) ? Wv : (which == 2) ? Wo : Wk;
    const int Kd = DMODEL, Nd = DMODEL;

#pragma unroll
    for (int p = 0; p < 4; ++p) {
        int c = tid + (p << 8);
        int r = c >> 4, c4 = (c & 15) << 2;
        *(float4*)&tile[r][c4] = *(const float4*)(W + (size_t)(k0 + r) * Nd + n0 + c4);
    }
    __syncthreads();
#pragma unroll
    for (int p = 0; p < 4; ++p) {
        int c = tid + (p << 8);
        int n = c >> 4, k4 = (c & 15) << 2;
        if (which < 3) {
            unsigned short* Wt = (which == 0) ? Wqt : (which == 1) ? Wvt : Wot;
            short4v o;
#pragma unroll
            for (int j = 0; j < 4; ++j) o[j] = (short)f2bf(tile[k4 + j][n]);
            *(short4v*)(Wt + (size_t)(n0 + n) * Kd + k0 + k4) = o;
        } else {
            short4v oh, ol;
#pragma unroll
            for (int j = 0; j < 4; ++j) {
                float v = tile[k4 + j][n];
                unsigned short hb = f2bf(v);
                oh[j] = (short)hb;
                ol[j] = (short)f2bf(v - bf2f(hb));
            }
            *(short4v*)(Wkh + (size_t)(n0 + n) * Kd + k0 + k4) = oh;
            *(short4v*)(Wkl + (size_t)(n0 + n) * Kd + k0 + k4) = ol;
        }
    }
}

// ---------------------------------------------------------------------------
// bf16 MFMA GEMM (OUT projection), 512 thr, 128x128 tile, 1D XCD-swizzled
// grid of 256: blk%8 == m%8 -> A-panels L2-resident per XCD.
// ---------------------------------------------------------------------------
__global__ __launch_bounds__(512)
void gemm_bf16_k(const unsigned short* __restrict__ A,
                 const unsigned short* __restrict__ Bt,
                 const float* __restrict__ bias,
                 float* __restrict__ out,
                 int M, int N, int K)
{
    __shared__ __align__(16) unsigned short As[128][72];
    __shared__ __align__(16) unsigned short Bs[128][72];
    const int tid = threadIdx.x;
    const int lane = tid & 63, wave = tid >> 6;
    const int quad = lane >> 4, ln = lane & 15;
    const int mh = (wave >> 2) << 6;
    const int nh = (wave & 3) << 5;
    // decode: blk = (m%8) + 8*((m/8) + 4*n), m in [0,32), n in [0,8)
    const int blk = blockIdx.x;
    const int xcd = blk & 7, t2 = blk >> 3;
    const int m0 = ((t2 & 3) * 8 + xcd) * 128, n0 = (t2 >> 2) * 128;

    f32x4 acc[4][2];
#pragma unroll
    for (int i = 0; i < 4; ++i)
#pragma unroll
        for (int j = 0; j < 2; ++j) acc[i][j] = (f32x4){0.f, 0.f, 0.f, 0.f};

    short8 areg[2], breg[2];
#pragma unroll
    for (int p = 0; p < 2; ++p) {
        int c = tid + (p << 9);
        int row = c >> 3, col8 = (c & 7) << 3;
        areg[p] = *(const short8*)(A + (size_t)(m0 + row) * K + col8);
        breg[p] = *(const short8*)(Bt + (size_t)(n0 + row) * K + col8);
    }

    for (int k0 = 0; k0 < K; k0 += 64) {
        __syncthreads();
#pragma unroll
        for (int p = 0; p < 2; ++p) {
            int c = tid + (p << 9);
            int row = c >> 3, col8 = (c & 7) << 3;
            *(short8*)&As[row][col8] = areg[p];
            *(short8*)&Bs[row][col8] = breg[p];
        }
        __syncthreads();
        if (k0 + 64 < K) {
#pragma unroll
            for (int p = 0; p < 2; ++p) {
                int c = tid + (p << 9);
                int row = c >> 3, col8 = (c & 7) << 3;
                areg[p] = *(const short8*)(A + (size_t)(m0 + row) * K + k0 + 64 + col8);
                breg[p] = *(const short8*)(Bt + (size_t)(n0 + row) * K + k0 + 64 + col8);
            }
        }
#pragma unroll
        for (int ch = 0; ch < 2; ++ch) {
            short8 af[4], bf[2];
#pragma unroll
            for (int mt = 0; mt < 4; ++mt)
                af[mt] = *(const short8*)&As[mh + mt * 16 + ln][ch * 32 + quad * 8];
#pragma unroll
            for (int nt = 0; nt < 2; ++nt)
                bf[nt] = *(const short8*)&Bs[nh + nt * 16 + ln][ch * 32 + quad * 8];
#pragma unroll
            for (int mt = 0; mt < 4; ++mt)
#pragma unroll
                for (int nt = 0; nt < 2; ++nt)
                    acc[mt][nt] = __builtin_amdgcn_mfma_f32_16x16x32_bf16(
                        af[mt], bf[nt], acc[mt][nt], 0, 0, 0);
        }
    }

#pragma unroll
    for (int mt = 0; mt < 4; ++mt)
#pragma unroll
        for (int nt = 0; nt < 2; ++nt)
#pragma unroll
            for (int r = 0; r < 4; ++r) {
                int m = m0 + mh + mt * 16 + quad * 4 + r;
                int n = n0 + nh + nt * 16 + ln;
                out[(size_t)m * N + n] = acc[mt][nt][r] + bias[n];
            }
}

// ---------------------------------------------------------------------------
// Merged projections, XCD-swizzled, LDS 40960B. Blocks [0,256) = kproj
// (compensated, 128x128, BK=32, [.][40] tiles, M2xN4) dispatched FIRST
// (3x FLOP of a QV block); blocks [256,768) = QV (128x128, BK=64).
// ---------------------------------------------------------------------------
__global__ __launch_bounds__(512)
void proj_qvk_k(const unsigned short* __restrict__ xh,
                const unsigned short* __restrict__ xl,
                const unsigned short* __restrict__ Wqt,
                const unsigned short* __restrict__ Wkh,
                const unsigned short* __restrict__ Wkl,
                unsigned short* __restrict__ qb,
                unsigned short* __restrict__ vb,
                unsigned short* __restrict__ vtout,
                unsigned short* __restrict__ kout,
                float* __restrict__ norms2)
{
    __shared__ __align__(16) unsigned short smem[20480];   // 40960 B
    const int blk = blockIdx.x;
    const int tid = threadIdx.x;
    const int lane = tid & 63, wave = tid >> 6;
    const int quad = lane >> 4, ln = lane & 15;
    const int K = DMODEL;

    if (blk >= 256) {
        // ---------------- QV path (128x128, BK=64) ----------------
        unsigned short* As = smem;            // [128][72]
        unsigned short* Bs = smem + 9216;
        const int qblk = blk - 256;
        const int xcd = qblk & 7, t2 = qblk >> 3;    // t2 = n + 16*(m/8)
        const int m0 = ((t2 >> 4) * 8 + xcd) * 128;  // m in [0,32)
        const int n0 = (t2 & 15) * 128;              // n in [0,16)
        const int mh = (wave >> 2) << 6;
        const int nh = (wave & 3) << 5;

        f32x4 acc[4][2];
#pragma unroll
        for (int i = 0; i < 4; ++i)
#pragma unroll
            for (int j = 0; j < 2; ++j) acc[i][j] = (f32x4){0.f, 0.f, 0.f, 0.f};

        short8 areg[2], breg[2];
#pragma unroll
        for (int p = 0; p < 2; ++p) {
            int c = tid + (p << 9);
            int row = c >> 3, col8 = (c & 7) << 3;
            areg[p] = *(const short8*)(xh + (size_t)(m0 + row) * K + col8);
            breg[p] = *(const short8*)(Wqt + (size_t)(n0 + row) * K + col8);
        }

        for (int k0 = 0; k0 < K; k0 += 64) {
            __syncthreads();
#pragma unroll
            for (int p = 0; p < 2; ++p) {
                int c = tid + (p << 9);
                int row = c >> 3, col8 = (c & 7) << 3;
                *(short8*)&As[row * 72 + col8] = areg[p];
                *(short8*)&Bs[row * 72 + col8] = breg[p];
            }
            __syncthreads();
            if (k0 + 64 < K) {
#pragma unroll
                for (int p = 0; p < 2; ++p) {
                    int c = tid + (p << 9);
                    int row = c >> 3, col8 = (c & 7) << 3;
                    areg[p] = *(const short8*)(xh + (size_t)(m0 + row) * K + k0 + 64 + col8);
                    breg[p] = *(const short8*)(Wqt + (size_t)(n0 + row) * K + k0 + 64 + col8);
                }
            }
#pragma unroll
            for (int ch = 0; ch < 2; ++ch) {
                short8 af[4], bf[2];
#pragma unroll
                for (int mt = 0; mt < 4; ++mt)
                    af[mt] = *(const short8*)&As[(mh + mt * 16 + ln) * 72 + ch * 32 + quad * 8];
#pragma unroll
                for (int nt = 0; nt < 2; ++nt)
                    bf[nt] = *(const short8*)&Bs[(nh + nt * 16 + ln) * 72 + ch * 32 + quad * 8];
#pragma unroll
                for (int mt = 0; mt < 4; ++mt)
#pragma unroll
                    for (int nt = 0; nt < 2; ++nt)
                        acc[mt][nt] = __builtin_amdgcn_mfma_f32_16x16x32_bf16(
                            af[mt], bf[nt], acc[mt][nt], 0, 0, 0);
            }
        }

#pragma unroll
        for (int mt = 0; mt < 4; ++mt)
#pragma unroll
            for (int nt = 0; nt < 2; ++nt) {
                int n = n0 + nh + nt * 16 + ln;
                int mb = m0 + mh + mt * 16 + quad * 4;
                int b = mb >> 11, s0 = mb & (SEQ - 1);
                int d = n & 63;
                if (n < DMODEL) {           // Q, pre-scaled incl. log2(e)
                    int h = n >> 6;
                    unsigned short* qp_ =
                        qb + ((size_t)(b * NH + h) * SEQ + s0) * DHEAD + d;
#pragma unroll
                    for (int r = 0; r < 4; ++r)
                        qp_[(size_t)r * DHEAD] = f2bf(acc[mt][nt][r] * 0.18033688f);
                } else {                    // V: row-major + transposed
                    int h = (n >> 6) - NH;
                    unsigned short* vp_ =
                        vb + ((size_t)(b * NH + h) * SEQ + s0) * DHEAD + d;
                    short4v tv;
#pragma unroll
                    for (int r = 0; r < 4; ++r) {
                        unsigned short bv = f2bf(acc[mt][nt][r]);
                        vp_[(size_t)r * DHEAD] = bv;
                        tv[r] = (short)bv;
                    }
                    *(short4v*)(vtout + ((size_t)(b * NH + h) * DHEAD + d) * SEQ + s0) = tv;
                }
            }
    } else {
        // ------- kproj path (compensated, 128x128, BK=32, M2xN4) -------
        unsigned short* Ah = smem;            // [128][40] each
        unsigned short* Al = smem + 5120;
        unsigned short* Bh = smem + 10240;
        unsigned short* Bl = smem + 15360;
        const int sb = blk;
        const int xcd = sb & 7, t2 = sb >> 3;        // t2 = (m/8) + 4*n
        const int m0 = ((t2 & 3) * 8 + xcd) * 128;   // m in [0,32)
        const int n0 = (t2 >> 2) * 128;              // n in [0,8)
        const int mh = (wave >> 1) << 5;      // 4 m-groups x 32 rows
        const int nh = (wave & 1) << 6;       // 2 n-groups x 64 cols

        f32x4 acc[2][4];
#pragma unroll
        for (int i = 0; i < 2; ++i)
#pragma unroll
            for (int j = 0; j < 4; ++j) acc[i][j] = (f32x4){0.f, 0.f, 0.f, 0.f};

        const int krow = tid >> 2, kcol8 = (tid & 3) << 3;   // 128 x 32
        short8 ahreg, alreg, bhreg, blreg;
        {
            size_t ga = (size_t)(m0 + krow) * K + kcol8;
            size_t gb = (size_t)(n0 + krow) * K + kcol8;
            ahreg = *(const short8*)(xh + ga);
            alreg = *(const short8*)(xl + ga);
            bhreg = *(const short8*)(Wkh + gb);
            blreg = *(const short8*)(Wkl + gb);
        }

        for (int k0 = 0; k0 < K; k0 += 32) {
            __syncthreads();
            *(short8*)&Ah[krow * 40 + kcol8] = ahreg;
            *(short8*)&Al[krow * 40 + kcol8] = alreg;
            *(short8*)&Bh[krow * 40 + kcol8] = bhreg;
            *(short8*)&Bl[krow * 40 + kcol8] = blreg;
            __syncthreads();
            if (k0 + 32 < K) {
                size_t ga = (size_t)(m0 + krow) * K + k0 + 32 + kcol8;
                size_t gb = (size_t)(n0 + krow) * K + k0 + 32 + kcol8;
                ahreg = *(const short8*)(xh + ga);
                alreg = *(const short8*)(xl + ga);
                bhreg = *(const short8*)(Wkh + gb);
                blreg = *(const short8*)(Wkl + gb);
            }
            short8 afh[2], afl[2];
#pragma unroll
            for (int mt = 0; mt < 2; ++mt) {
                afh[mt] = *(const short8*)&Ah[(mh + mt * 16 + ln) * 40 + quad * 8];
                afl[mt] = *(const short8*)&Al[(mh + mt * 16 + ln) * 40 + quad * 8];
            }
#pragma unroll
            for (int nt = 0; nt < 4; ++nt) {
                short8 bfh = *(const short8*)&Bh[(nh + nt * 16 + ln) * 40 + quad * 8];
                short8 bfl = *(const short8*)&Bl[(nh + nt * 16 + ln) * 40 + quad * 8];
#pragma unroll
                for (int mt = 0; mt < 2; ++mt) {
                    acc[mt][nt] = __builtin_amdgcn_mfma_f32_16x16x32_bf16(afh[mt], bfh, acc[mt][nt], 0, 0, 0);
                    acc[mt][nt] = __builtin_amdgcn_mfma_f32_16x16x32_bf16(afh[mt], bfl, acc[mt][nt], 0, 0, 0);
                    acc[mt][nt] = __builtin_amdgcn_mfma_f32_16x16x32_bf16(afl[mt], bfh, acc[mt][nt], 0, 0, 0);
                }
            }
        }

        const int h = (n0 + nh) >> 6;
#pragma unroll
        for (int mt = 0; mt < 2; ++mt)
#pragma unroll
            for (int r = 0; r < 4; ++r) {
                int m = m0 + mh + mt * 16 + quad * 4 + r;
                int b = m >> 11, s = m & (SEQ - 1);
                size_t rowbase = ((size_t)(b * NH + h) * SEQ + s) * DHEAD;
#pragma unroll
                for (int nt = 0; nt < 4; ++nt)
                    kout[rowbase + nt * 16 + ln] = f2bf(acc[mt][nt][r]);
                float s2 = acc[mt][0][r] * acc[mt][0][r] + acc[mt][1][r] * acc[mt][1][r] +
                           acc[mt][2][r] * acc[mt][2][r] + acc[mt][3][r] * acc[mt][3][r];
#pragma unroll
                for (int off = 1; off <= 8; off <<= 1)
                    s2 += __shfl_xor(s2, off);
                if (ln == 0)
                    norms2[(size_t)(b * NH + h) * SEQ + s] = s2;
            }
    }
}

// ---------------------------------------------------------------------------
// topk + gather fused, 1024 threads (2 CE/thread over 66 bitonic stages).
// ---------------------------------------------------------------------------
__global__ __launch_bounds__(1024)
void topk_gather_k(const float* __restrict__ norms2,
                   const unsigned short* __restrict__ k,
                   const unsigned short* __restrict__ v,
                   unsigned short* __restrict__ gk,
                   unsigned short* __restrict__ gvt)
{
    __shared__ unsigned long long keys[SEQ];
    __shared__ int tix[NGPAD];
    __shared__ __align__(16) unsigned short T[64][72];
    const int bh = blockIdx.x;
    const int tid = threadIdx.x;
    const float* nb = norms2 + (size_t)bh * SEQ;
    const size_t base = (size_t)bh * SEQ * DHEAD;

    for (int i = tid; i < SEQ; i += 1024) {
        float nrm = sqrtf(nb[i]);
        keys[i] = ((unsigned long long)__float_as_uint(nrm) << 32) |
                  (unsigned int)(0xFFFFFFFFu - (unsigned int)i);
    }
    __syncthreads();
    for (int kk = 2; kk <= SEQ; kk <<= 1) {
        for (int j = kk >> 1; j > 0; j >>= 1) {
            for (int i = tid; i < SEQ; i += 1024) {
                int ixj = i ^ j;
                if (ixj > i) {
                    unsigned long long a = keys[i], b = keys[ixj];
                    bool up = ((i & kk) == 0);
                    if ((a > b) == up) { keys[i] = b; keys[ixj] = a; }
                }
            }
            __syncthreads();
        }
    }
    if (tid < NGPAD) {
        tix[tid] = (tid < NG)
            ? (int)(0xFFFFFFFFu - (unsigned int)(keys[SEQ - 1 - tid] & 0xFFFFFFFFu))
            : 0;
    }
    __syncthreads();

    for (int t = 0; t < NGPAD / 64; ++t) {
        {
            int row = tid >> 4, col4 = (tid & 15) << 2;   // 64 rows x 64 cols
            int g = t * 64 + row;
            short4v kv = (short4v)0, vv = (short4v)0;
            if (g < NG) {
                int sidx = tix[g];
                kv = *(const short4v*)(k + base + (size_t)sidx * DHEAD + col4);
                vv = *(const short4v*)(v + base + (size_t)sidx * DHEAD + col4);
            }
            *(short4v*)(gk + ((size_t)bh * NGPAD + g) * DHEAD + col4) = kv;
            *(short4v*)&T[row][col4] = vv;
        }
        __syncthreads();
        {
            int d = tid >> 4, k4 = (tid & 15) << 2;
            short4v o;
#pragma unroll
            for (int i = 0; i < 4; ++i) o[i] = (short)T[k4 + i][d];
            *(short4v*)(gvt + ((size_t)bh * DHEAD + d) * NGPAD + t * 64 + k4) = o;
        }
        __syncthreads();
    }
}

// ---------------------------------------------------------------------------
// Fused attention (r19, unchanged): 256 thr, 4 waves x 32 q-rows, swapped
// QK^T, P in registers as mfma32 A-frags via phi K-row permutation; K/V
// double-buffered; row-sums via ones-MFMA; Wg gate direct from global.
// ---------------------------------------------------------------------------
__global__ __launch_bounds__(256, 2)
void attn_fused_k(const unsigned short* __restrict__ qb,
                  const unsigned short* __restrict__ kb,
                  const unsigned short* __restrict__ vt,
                  const unsigned short* __restrict__ gk,
                  const unsigned short* __restrict__ gvt,
                  const unsigned short* __restrict__ Wgt,
                  const float* __restrict__ gamma,
                  const float* __restrict__ beta,
                  const float* __restrict__ bg,
                  unsigned short* __restrict__ fused)
{
    // smem layout (shorts): [0,9216) Ks[2][64][72]  (= Ps[128][72] alias)
    //                       [9216,18432) Vt[2][64][72]
    __shared__ __align__(16) unsigned short smem[18432];
    unsigned short* const KsB = smem;
    unsigned short* const VtB = smem + 9216;
    unsigned short (*Ps)[72]  = (unsigned short (*)[72])smem;

    const int flat = blockIdx.x;
    const int bh = ((flat >> 7) << 3) | (flat & 7);   // flat%8 == bh%8 (XCD)
    const int q0 = ((flat >> 3) & 15) * 128;
    const int tid = threadIdx.x;
    const int lane = tid & 63, wave = tid >> 6;       // 4 waves
    const int quad = lane >> 4, ln = lane & 15;
    const size_t base = (size_t)bh * SEQ * DHEAD;
    const unsigned short* gkb = gk + (size_t)bh * NGPAD * DHEAD;
    const unsigned short* gvb = gvt + (size_t)bh * DHEAD * NGPAD;

    short8 qf[2][2];
#pragma unroll
    for (int mt = 0; mt < 2; ++mt) {
        const unsigned short* qp = qb + base + (size_t)(q0 + wave * 32 + mt * 16 + ln) * DHEAD;
        qf[mt][0] = *(const short8*)(qp + quad * 8);
        qf[mt][1] = *(const short8*)(qp + 32 + quad * 8);
    }

    // ones / last-tile-mask B-frags for row-sum MFMAs
    short8 onesv, maskv;
#pragma unroll
    for (int j = 0; j < 8; ++j) {
        onesv[j] = (short)0x3F80;                              // bf16 1.0
        maskv[j] = (short)((quad * 8 + j) < 12 ? 0x3F80 : 0);  // NG-192=12
    }

    f32x4 O[2][4], Og[2][4], lsacc[2], lgacc[2];
#pragma unroll
    for (int mt = 0; mt < 2; ++mt) {
#pragma unroll
        for (int nt = 0; nt < 4; ++nt) {
            O[mt][nt] = (f32x4){0.f, 0.f, 0.f, 0.f};
            Og[mt][nt] = (f32x4){0.f, 0.f, 0.f, 0.f};
        }
        lsacc[mt] = (f32x4){0.f, 0.f, 0.f, 0.f};
        lgacc[mt] = (f32x4){0.f, 0.f, 0.f, 0.f};
    }

    short8 kreg[2], vreg[2];
    int srow[2], scol8[2], psrow[2];
#pragma unroll
    for (int p = 0; p < 2; ++p) {
        int idx = tid + (p << 8);
        srow[p] = idx >> 3;
        scol8[p] = (idx & 7) << 3;
        // phi: [b5 | b3 b2 | b4 | b1 b0]  (K-row permutation, verified r14)
        psrow[p] = (srow[p] & 0x20) | ((srow[p] & 0x0C) << 1) |
                   ((srow[p] & 0x10) >> 2) | (srow[p] & 3);
    }

    auto loadT = [&](int i) {
#pragma unroll
        for (int p = 0; p < 2; ++p) {
            if (i < 32) {
                kreg[p] = *(const short8*)(kb + base + (size_t)(i * 64 + psrow[p]) * DHEAD + scol8[p]);
                vreg[p] = *(const short8*)(vt + base + (size_t)srow[p] * SEQ + i * 64 + scol8[p]);
            } else {
                int g = i - 32;
                kreg[p] = *(const short8*)(gkb + (size_t)(g * 64 + psrow[p]) * DHEAD + scol8[p]);
                vreg[p] = *(const short8*)(gvb + (size_t)srow[p] * NGPAD + g * 64 + scol8[p]);
            }
        }
    };
    auto storeT = [&](int buf) {
        unsigned short* kd = KsB + buf * 4608;
        unsigned short* vd = VtB + buf * 4608;
#pragma unroll
        for (int p = 0; p < 2; ++p) {
            *(short8*)&kd[srow[p] * 72 + scol8[p]] = kreg[p];
            *(short8*)&vd[srow[p] * 72 + scol8[p]] = vreg[p];
        }
    };

    loadT(0);
    storeT(0);
    loadT(1);
    __syncthreads();

    // ---- local: 32 tiles ----
    for (int t = 0; t < 32; ++t) {
        const int cur = t & 1;
        const unsigned short* Kc = KsB + cur * 4608;
        const unsigned short* Vc = VtB + cur * 4608;

        // swapped QK^T: lane holds S^T[k_phys = phi(nt*16+quad*4+r)][q=ln]
        f32x4 s[2][4];
#pragma unroll
        for (int mt = 0; mt < 2; ++mt)
#pragma unroll
            for (int nt = 0; nt < 4; ++nt) s[mt][nt] = (f32x4){0.f, 0.f, 0.f, 0.f};
        __builtin_amdgcn_s_setprio(1);
#pragma unroll
        for (int nt = 0; nt < 4; ++nt) {
            short8 kf0 = *(const short8*)&Kc[(nt * 16 + ln) * 72 + quad * 8];
            short8 kf1 = *(const short8*)&Kc[(nt * 16 + ln) * 72 + 32 + quad * 8];
#pragma unroll
            for (int mt = 0; mt < 2; ++mt) {
                s[mt][nt] = __builtin_amdgcn_mfma_f32_16x16x32_bf16(kf0, qf[mt][0], s[mt][nt], 0, 0, 0);
                s[mt][nt] = __builtin_amdgcn_mfma_f32_16x16x32_bf16(kf1, qf[mt][1], s[mt][nt], 0, 0, 0);
            }
        }
        __builtin_amdgcn_s_setprio(0);

        // exp + pack into mfma32 A-frags: pf8[mt][c] = k_phys c*32+quad*8+[0..7]
        short8 pf8[2][2];
#pragma unroll
        for (int mt = 0; mt < 2; ++mt)
#pragma unroll
            for (int nt = 0; nt < 4; ++nt)
#pragma unroll
                for (int r = 0; r < 4; ++r) {
                    unsigned int u = __float_as_uint(__builtin_amdgcn_exp2f(s[mt][nt][r]));
                    pf8[mt][nt >> 1][((nt & 1) << 2) | r] = (short)(u >> 16);
                }

        // PV + row-sum: full-rate mfma32, P from registers
        __builtin_amdgcn_s_setprio(1);
#pragma unroll
        for (int dt = 0; dt < 4; ++dt)
#pragma unroll
            for (int c = 0; c < 2; ++c) {
                short8 vf = *(const short8*)&Vc[(dt * 16 + ln) * 72 + c * 32 + quad * 8];
#pragma unroll
                for (int mt = 0; mt < 2; ++mt)
                    O[mt][dt] = __builtin_amdgcn_mfma_f32_16x16x32_bf16(
                        pf8[mt][c], vf, O[mt][dt], 0, 0, 0);
            }
#pragma unroll
        for (int c = 0; c < 2; ++c)
#pragma unroll
            for (int mt = 0; mt < 2; ++mt)
                lsacc[mt] = __builtin_amdgcn_mfma_f32_16x16x32_bf16(
                    pf8[mt][c], onesv, lsacc[mt], 0, 0, 0);
        __builtin_amdgcn_s_setprio(0);

        storeT(cur ^ 1);            // tile t+1 -> other buffer
        if (t + 2 <= 35) loadT(t + 2);
        __syncthreads();
    }

    // ---- global: 4 gathered tiles (padded rows: K=0 -> P=1, V=0; mask
    //      excludes them from lgacc; tiles 0-2 fully valid) ----
    for (int tg = 0; tg < 4; ++tg) {
        const int t = 32 + tg;
        const int cur = t & 1;
        const unsigned short* Kc = KsB + cur * 4608;
        const unsigned short* Vc = VtB + cur * 4608;

        f32x4 s[2][4];
#pragma unroll
        for (int mt = 0; mt < 2; ++mt)
#pragma unroll
            for (int nt = 0; nt < 4; ++nt) s[mt][nt] = (f32x4){0.f, 0.f, 0.f, 0.f};
        __builtin_amdgcn_s_setprio(1);
#pragma unroll
        for (int nt = 0; nt < 4; ++nt) {
            short8 kf0 = *(const short8*)&Kc[(nt * 16 + ln) * 72 + quad * 8];
            short8 kf1 = *(const short8*)&Kc[(nt * 16 + ln) * 72 + 32 + quad * 8];
#pragma unroll
            for (int mt = 0; mt < 2; ++mt) {
                s[mt][nt] = __builtin_amdgcn_mfma_f32_16x16x32_bf16(kf0, qf[mt][0], s[mt][nt], 0, 0, 0);
                s[mt][nt] = __builtin_amdgcn_mfma_f32_16x16x32_bf16(kf1, qf[mt][1], s[mt][nt], 0, 0, 0);
            }
        }
        __builtin_amdgcn_s_setprio(0);

        short8 pf8[2][2];
#pragma unroll
        for (int mt = 0; mt < 2; ++mt)
#pragma unroll
            for (int nt = 0; nt < 4; ++nt)
#pragma unroll
                for (int r = 0; r < 4; ++r) {
                    unsigned int u = __float_as_uint(__builtin_amdgcn_exp2f(s[mt][nt][r]));
                    pf8[mt][nt >> 1][((nt & 1) << 2) | r] = (short)(u >> 16);
                }

        __builtin_amdgcn_s_setprio(1);
#pragma unroll
        for (int dt = 0; dt < 4; ++dt)
#pragma unroll
            for (int c = 0; c < 2; ++c) {
                short8 vf = *(const short8*)&Vc[(dt * 16 + ln) * 72 + c * 32 + quad * 8];
#pragma unroll
                for (int mt = 0; mt < 2; ++mt)
                    Og[mt][dt] = __builtin_amdgcn_mfma_f32_16x16x32_bf16(
                        pf8[mt][c], vf, Og[mt][dt], 0, 0, 0);
            }
        if (tg < 3) {
#pragma unroll
            for (int c = 0; c < 2; ++c)
#pragma unroll
                for (int mt = 0; mt < 2; ++mt)
                    lgacc[mt] = __builtin_amdgcn_mfma_f32_16x16x32_bf16(
                        pf8[mt][c], onesv, lgacc[mt], 0, 0, 0);
        } else {
            // last tile: only k_phys < 12 valid (c=0 chunk), via maskv
#pragma unroll
            for (int mt = 0; mt < 2; ++mt)
                lgacc[mt] = __builtin_amdgcn_mfma_f32_16x16x32_bf16(
                    pf8[mt][0], maskv, lgacc[mt], 0, 0, 0);
        }
        __builtin_amdgcn_s_setprio(0);

        if (t < 35) storeT(cur ^ 1);
        if (t + 2 <= 35) loadT(t + 2);
        __syncthreads();            // last iter: protects Ps alias in epilogue
    }

    // ---- row sums already in O layout (q = quad*4+r) ----
    float invl[2][4], invg[2][4];
#pragma unroll
    for (int mt = 0; mt < 2; ++mt)
#pragma unroll
        for (int r = 0; r < 4; ++r) {
            invl[mt][r] = 1.f / lsacc[mt][r];
            invg[mt][r] = 1.f / lgacc[mt][r];
        }

    // ---- layernorm(global) ----
    float xs[2][4][4];
#pragma unroll
    for (int mt = 0; mt < 2; ++mt)
#pragma unroll
        for (int r = 0; r < 4; ++r) {
            float inv = invg[mt][r];
#pragma unroll
            for (int nt = 0; nt < 4; ++nt) xs[mt][nt][r] = Og[mt][nt][r] * inv;
        }
    float mu[2][4], rsd[2][4];
#pragma unroll
    for (int mt = 0; mt < 2; ++mt)
#pragma unroll
        for (int r = 0; r < 4; ++r) {
            float sm = xs[mt][0][r] + xs[mt][1][r] + xs[mt][2][r] + xs[mt][3][r];
#pragma unroll
            for (int off = 1; off <= 8; off <<= 1) sm += __shfl_xor(sm, off);
            mu[mt][r] = sm * (1.f / 64.f);
        }
#pragma unroll
    for (int mt = 0; mt < 2; ++mt)
#pragma unroll
        for (int r = 0; r < 4; ++r) {
            float sv = 0.f;
#pragma unroll
            for (int nt = 0; nt < 4; ++nt) {
                float d = xs[mt][nt][r] - mu[mt][r];
                sv += d * d;
            }
#pragma unroll
            for (int off = 1; off <= 8; off <<= 1) sv += __shfl_xor(sv, off);
            rsd[mt][r] = rsqrtf(sv * (1.f / 64.f) + LNEPS);
        }
#pragma unroll
    for (int nt = 0; nt < 4; ++nt) {
        float g = gamma[nt * 16 + ln], bb = beta[nt * 16 + ln];
#pragma unroll
        for (int mt = 0; mt < 2; ++mt)
#pragma unroll
            for (int r = 0; r < 4; ++r)
                xs[mt][nt][r] = (xs[mt][nt][r] - mu[mt][r]) * rsd[mt][r] * g + bb;
    }

    // ---- gate via MFMA (Ps alias; intra-wave rows, no barrier; Wg from
    //      global Wgt - r14-verified path) ----
    float lf[2][4][4];
#pragma unroll
    for (int mt = 0; mt < 2; ++mt)
#pragma unroll
        for (int nt = 0; nt < 4; ++nt)
#pragma unroll
            for (int r = 0; r < 4; ++r) {
                lf[mt][nt][r] = O[mt][nt][r] * invl[mt][r];
                Ps[wave * 32 + mt * 16 + quad * 4 + r][nt * 16 + ln] = f2bf(lf[mt][nt][r]);
            }
    f32x4 gacc[2][4];
#pragma unroll
    for (int ng = 0; ng < 4; ++ng) {
        float bgv = bg[ng * 16 + ln];
#pragma unroll
        for (int mt = 0; mt < 2; ++mt)
            gacc[mt][ng] = (f32x4){bgv, bgv, bgv, bgv};
    }
#pragma unroll
    for (int ch = 0; ch < 2; ++ch) {
        short8 af[2];
#pragma unroll
        for (int mt = 0; mt < 2; ++mt)
            af[mt] = *(const short8*)&Ps[wave * 32 + mt * 16 + ln][ch * 32 + quad * 8];
#pragma unroll
        for (int ng = 0; ng < 4; ++ng) {
            short8 bf = *(const short8*)(Wgt + (size_t)(ng * 16 + ln) * 128 + ch * 32 + quad * 8);
#pragma unroll
            for (int mt = 0; mt < 2; ++mt)
                gacc[mt][ng] = __builtin_amdgcn_mfma_f32_16x16x32_bf16(af[mt], bf, gacc[mt][ng], 0, 0, 0);
        }
    }
#pragma unroll
    for (int mt = 0; mt < 2; ++mt)
#pragma unroll
        for (int nt = 0; nt < 4; ++nt)
#pragma unroll
            for (int r = 0; r < 4; ++r)
                Ps[wave * 32 + mt * 16 + quad * 4 + r][nt * 16 + ln] = f2bf(xs[mt][nt][r]);
#pragma unroll
    for (int ch = 0; ch < 2; ++ch) {
        short8 af[2];
#pragma unroll
        for (int mt = 0; mt < 2; ++mt)
            af[mt] = *(const short8*)&Ps[wave * 32 + mt * 16 + ln][ch * 32 + quad * 8];
#pragma unroll
        for (int ng = 0; ng < 4; ++ng) {
            short8 bf = *(const short8*)(Wgt + (size_t)(ng * 16 + ln) * 128 + 64 + ch * 32 + quad * 8);
#pragma unroll
            for (int mt = 0; mt < 2; ++mt)
                gacc[mt][ng] = __builtin_amdgcn_mfma_f32_16x16x32_bf16(af[mt], bf, gacc[mt][ng], 0, 0, 0);
        }
    }

    // ---- fuse + store ----
    const int b = bh >> 4, h = bh & 15;
#pragma unroll
    for (int mt = 0; mt < 2; ++mt)
#pragma unroll
        for (int ng = 0; ng < 4; ++ng)
#pragma unroll
            for (int r = 0; r < 4; ++r) {
                float gt = 1.f / (1.f + __expf(-gacc[mt][ng][r]));
                float f = gt * lf[mt][ng][r] + (1.f - gt) * xs[mt][ng][r];
                int s = q0 + wave * 32 + mt * 16 + quad * 4 + r;
                fused[((size_t)(b * SEQ + s)) * DMODEL + h * DHEAD + ng * 16 + ln] = f2bf(f);
            }
}

// ---------------------------------------------------------------------------
extern "C" void kernel_launch(void* const* d_in, const int* in_sizes, int n_in,
                              void* d_out, int out_size, void* d_ws, size_t ws_size,
                              hipStream_t stream)
{
    (void)in_sizes; (void)n_in; (void)out_size; (void)ws_size;
    const float* x    = (const float*)d_in[0];
    const float* Wq   = (const float*)d_in[1];
    const float* Wk   = (const float*)d_in[2];
    const float* Wv   = (const float*)d_in[3];
    const float* Wo   = (const float*)d_in[4];
    const float* bo   = (const float*)d_in[5];
    const float* ln_g = (const float*)d_in[6];
    const float* ln_b = (const float*)d_in[7];
    const float* Wg   = (const float*)d_in[8];
    const float* bg   = (const float*)d_in[9];

    char* w = (char*)d_ws;
    const size_t MB = 1024ull * 1024ull;
    unsigned short* kb16  = (unsigned short*)(w);
    unsigned short* qb16  = (unsigned short*)(w + 8 * MB);
    unsigned short* vb16  = (unsigned short*)(w + 16 * MB);
    unsigned short* vt16  = (unsigned short*)(w + 24 * MB);
    unsigned short* xh    = (unsigned short*)(w + 32 * MB);
    unsigned short* xl    = (unsigned short*)(w + 40 * MB);
    unsigned short* Wqt   = (unsigned short*)(w + 48 * MB);
    unsigned short* Wvt   = (unsigned short*)(w + 50 * MB);   // contiguous after Wqt
    unsigned short* Wot   = (unsigned short*)(w + 52 * MB);
    unsigned short* Wkh   = (unsigned short*)(w + 54 * MB);
    unsigned short* Wkl   = (unsigned short*)(w + 56 * MB);
    unsigned short* Wgt   = (unsigned short*)(w + 58 * MB);
    float*          norms2= (float*)(w + 59 * MB);
    unsigned short* gk16  = (unsigned short*)(w + 60 * MB);
    unsigned short* gvt16 = (unsigned short*)(w + 61 * MB);
    unsigned short* fusedb = xh;   // xh dead after projections
    (void)Wvt;

    const int M = 4096, N = 1024, K = 1024;

    prep_k<<<3073, 256, 0, stream>>>(x, Wq, Wv, Wo, Wk, Wg,
                                     xh, xl, Wqt, Wvt, Wot, Wkh, Wkl, Wgt);

    proj_qvk_k<<<768, 512, 0, stream>>>(xh, xl, Wqt, Wkh, Wkl,
                                        qb16, vb16, vt16, kb16, norms2);

    topk_gather_k<<<BHT, 1024, 0, stream>>>(norms2, kb16, vb16, gk16, gvt16);

    attn_fused_k<<<512, 256, 0, stream>>>(qb16, kb16, vt16, gk16, gvt16, Wgt,
                                          ln_g, ln_b, bg, fusedb);

    gemm_bf16_k<<<256, 512, 0, stream>>>(fusedb, Wot, bo, (float*)d_out,
                                         M, N, K);
}

// Round 13
// 245.343 us; speedup vs baseline: 1.0282x; 1.0282x over previous
//
#include <hip/hip_runtime.h>

// SegmentedAttention round 22 = exact revert to r19 (measured best 243.4us).
// r20 (64x128 kproj split) and r21 (kproj-first dispatch) BOTH regressed
// proj (61 -> 69 -> 69.9us; FETCH 50 -> 57 -> 59.5MB). Conclusion: proj's
// ~61us is the structural floor of the barrier-lockstep k-loop (vmcnt(0)
// drain per tile); scheduling/locality/occupancy knobs don't move it, and
// the gload_lds+counted-vmcnt pipeline rewrite is multi-round risk.
// r22 locks in the best-known configuration: QV blocks [0,512) first,
// kproj [512,768) (128x128, BK=32, [.][40]); attn r19; topk 1024thr;
// out-gemm XCD-swizzled.
// ws (MB): kb16@0(8) qb16@8(8) vb16@16(8) vt16@24(8) xh@32(8,=fusedb)
//   xl@40(8) Wqt@48(2) Wvt@50(2) Wot@52(2) Wkh@54(2) Wkl@56(2) Wgt@58(1)
//   norms2@59(1) gk@60(1) gvt@61(1) -> 62MB

constexpr int SEQ    = 2048;
constexpr int DMODEL = 1024;
constexpr int NH     = 16;
constexpr int DHEAD  = 64;
constexpr int BHT    = 32;
constexpr int NG     = 204;
constexpr int NGPAD  = 256;
constexpr float LNEPS = 1e-5f;

typedef __attribute__((ext_vector_type(8))) short short8;
typedef __attribute__((ext_vector_type(4))) short short4v;
typedef __attribute__((ext_vector_type(4))) float f32x4;

__device__ __forceinline__ unsigned short f2bf(float f) {
    unsigned int u = __float_as_uint(f);
    u += 0x7FFFu + ((u >> 16) & 1u);
    return (unsigned short)(u >> 16);
}
__device__ __forceinline__ float bf2f(unsigned short b) {
    return __uint_as_float(((unsigned int)b) << 16);
}

// ---------------------------------------------------------------------------
// prep: blocks [0,2048): x hilo split; [2048,3072): weight transposes;
// block 3072: Wg^T bf16.
// ---------------------------------------------------------------------------
__global__ __launch_bounds__(256)
void prep_k(const float* __restrict__ x,
            const float* __restrict__ Wq, const float* __restrict__ Wv,
            const float* __restrict__ Wo, const float* __restrict__ Wk,
            const float* __restrict__ Wg,
            unsigned short* __restrict__ xh, unsigned short* __restrict__ xl,
            unsigned short* __restrict__ Wqt, unsigned short* __restrict__ Wvt,
            unsigned short* __restrict__ Wot, unsigned short* __restrict__ Wkh,
            unsigned short* __restrict__ Wkl, unsigned short* __restrict__ Wgt)
{
    const int bid = blockIdx.x;
    const int tid = threadIdx.x;

    if (bid < 2048) {
        int i = (bid * 256 + tid) << 3;
        short8 h, l;
#pragma unroll
        for (int j = 0; j < 8; ++j) {
            float v = x[i + j];
            unsigned short hb = f2bf(v);
            h[j] = (short)hb;
            l[j] = (short)f2bf(v - bf2f(hb));
        }
        *(short8*)(xh + i) = h;
        *(short8*)(xl + i) = l;
        return;
    }
    if (bid == 3072) {
#pragma unroll
        for (int i = 0; i < 32; ++i) {
            int o = tid * 32 + i;
            int dg = o >> 7, jj = o & 127;
            Wgt[o] = f2bf(Wg[jj * 64 + dg]);
        }
        return;
    }

    __shared__ float tile[64][68];
    const int sub = bid - 2048;
    const int which = sub >> 8;             // 0:Wq 1:Wv 2:Wo 3:Wk
    const int b = sub & 255;
    const int n0 = (b & 15) * 64, k0 = (b >> 4) * 64;
    const float* W = (which == 0) ? Wq : (which == 1) ? Wv : (which == 2) ? Wo : Wk;
    const int Kd = DMODEL, Nd = DMODEL;

#pragma unroll
    for (int p = 0; p < 4; ++p) {
        int c = tid + (p << 8);
        int r = c >> 4, c4 = (c & 15) << 2;
        *(float4*)&tile[r][c4] = *(const float4*)(W + (size_t)(k0 + r) * Nd + n0 + c4);
    }
    __syncthreads();
#pragma unroll
    for (int p = 0; p < 4; ++p) {
        int c = tid + (p << 8);
        int n = c >> 4, k4 = (c & 15) << 2;
        if (which < 3) {
            unsigned short* Wt = (which == 0) ? Wqt : (which == 1) ? Wvt : Wot;
            short4v o;
#pragma unroll
            for (int j = 0; j < 4; ++j) o[j] = (short)f2bf(tile[k4 + j][n]);
            *(short4v*)(Wt + (size_t)(n0 + n) * Kd + k0 + k4) = o;
        } else {
            short4v oh, ol;
#pragma unroll
            for (int j = 0; j < 4; ++j) {
                float v = tile[k4 + j][n];
                unsigned short hb = f2bf(v);
                oh[j] = (short)hb;
                ol[j] = (short)f2bf(v - bf2f(hb));
            }
            *(short4v*)(Wkh + (size_t)(n0 + n) * Kd + k0 + k4) = oh;
            *(short4v*)(Wkl + (size_t)(n0 + n) * Kd + k0 + k4) = ol;
        }
    }
}

// ---------------------------------------------------------------------------
// bf16 MFMA GEMM (OUT projection), 512 thr, 128x128 tile, 1D XCD-swizzled
// grid of 256: blk%8 == m%8 -> A-panels L2-resident per XCD.
// ---------------------------------------------------------------------------
__global__ __launch_bounds__(512)
void gemm_bf16_k(const unsigned short* __restrict__ A,
                 const unsigned short* __restrict__ Bt,
                 const float* __restrict__ bias,
                 float* __restrict__ out,
                 int M, int N, int K)
{
    __shared__ __align__(16) unsigned short As[128][72];
    __shared__ __align__(16) unsigned short Bs[128][72];
    const int tid = threadIdx.x;
    const int lane = tid & 63, wave = tid >> 6;
    const int quad = lane >> 4, ln = lane & 15;
    const int mh = (wave >> 2) << 6;
    const int nh = (wave & 3) << 5;
    // decode: blk = (m%8) + 8*((m/8) + 4*n), m in [0,32), n in [0,8)
    const int blk = blockIdx.x;
    const int xcd = blk & 7, t2 = blk >> 3;
    const int m0 = ((t2 & 3) * 8 + xcd) * 128, n0 = (t2 >> 2) * 128;

    f32x4 acc[4][2];
#pragma unroll
    for (int i = 0; i < 4; ++i)
#pragma unroll
        for (int j = 0; j < 2; ++j) acc[i][j] = (f32x4){0.f, 0.f, 0.f, 0.f};

    short8 areg[2], breg[2];
#pragma unroll
    for (int p = 0; p < 2; ++p) {
        int c = tid + (p << 9);
        int row = c >> 3, col8 = (c & 7) << 3;
        areg[p] = *(const short8*)(A + (size_t)(m0 + row) * K + col8);
        breg[p] = *(const short8*)(Bt + (size_t)(n0 + row) * K + col8);
    }

    for (int k0 = 0; k0 < K; k0 += 64) {
        __syncthreads();
#pragma unroll
        for (int p = 0; p < 2; ++p) {
            int c = tid + (p << 9);
            int row = c >> 3, col8 = (c & 7) << 3;
            *(short8*)&As[row][col8] = areg[p];
            *(short8*)&Bs[row][col8] = breg[p];
        }
        __syncthreads();
        if (k0 + 64 < K) {
#pragma unroll
            for (int p = 0; p < 2; ++p) {
                int c = tid + (p << 9);
                int row = c >> 3, col8 = (c & 7) << 3;
                areg[p] = *(const short8*)(A + (size_t)(m0 + row) * K + k0 + 64 + col8);
                breg[p] = *(const short8*)(Bt + (size_t)(n0 + row) * K + k0 + 64 + col8);
            }
        }
#pragma unroll
        for (int ch = 0; ch < 2; ++ch) {
            short8 af[4], bf[2];
#pragma unroll
            for (int mt = 0; mt < 4; ++mt)
                af[mt] = *(const short8*)&As[mh + mt * 16 + ln][ch * 32 + quad * 8];
#pragma unroll
            for (int nt = 0; nt < 2; ++nt)
                bf[nt] = *(const short8*)&Bs[nh + nt * 16 + ln][ch * 32 + quad * 8];
#pragma unroll
            for (int mt = 0; mt < 4; ++mt)
#pragma unroll
                for (int nt = 0; nt < 2; ++nt)
                    acc[mt][nt] = __builtin_amdgcn_mfma_f32_16x16x32_bf16(
                        af[mt], bf[nt], acc[mt][nt], 0, 0, 0);
        }
    }

#pragma unroll
    for (int mt = 0; mt < 4; ++mt)
#pragma unroll
        for (int nt = 0; nt < 2; ++nt)
#pragma unroll
            for (int r = 0; r < 4; ++r) {
                int m = m0 + mh + mt * 16 + quad * 4 + r;
                int n = n0 + nh + nt * 16 + ln;
                out[(size_t)m * N + n] = acc[mt][nt][r] + bias[n];
            }
}

// ---------------------------------------------------------------------------
// Merged projections, XCD-swizzled, LDS 40960B. Blocks [0,512) = QV
// (128x128, BK=64); blocks [512,768) = kproj (compensated, 128x128,
// BK=32, [.][40] tiles, M2xN4).  (r19 layout - measured best.)
// ---------------------------------------------------------------------------
__global__ __launch_bounds__(512)
void proj_qvk_k(const unsigned short* __restrict__ xh,
                const unsigned short* __restrict__ xl,
                const unsigned short* __restrict__ Wqt,
                const unsigned short* __restrict__ Wkh,
                const unsigned short* __restrict__ Wkl,
                unsigned short* __restrict__ qb,
                unsigned short* __restrict__ vb,
                unsigned short* __restrict__ vtout,
                unsigned short* __restrict__ kout,
                float* __restrict__ norms2)
{
    __shared__ __align__(16) unsigned short smem[20480];   // 40960 B
    const int blk = blockIdx.x;
    const int tid = threadIdx.x;
    const int lane = tid & 63, wave = tid >> 6;
    const int quad = lane >> 4, ln = lane & 15;
    const int K = DMODEL;

    if (blk < 512) {
        // ---------------- QV path (128x128, BK=64) ----------------
        unsigned short* As = smem;            // [128][72]
        unsigned short* Bs = smem + 9216;
        const int xcd = blk & 7, t2 = blk >> 3;      // t2 = n + 16*(m/8)
        const int m0 = ((t2 >> 4) * 8 + xcd) * 128;  // m in [0,32)
        const int n0 = (t2 & 15) * 128;              // n in [0,16)
        const int mh = (wave >> 2) << 6;
        const int nh = (wave & 3) << 5;

        f32x4 acc[4][2];
#pragma unroll
        for (int i = 0; i < 4; ++i)
#pragma unroll
            for (int j = 0; j < 2; ++j) acc[i][j] = (f32x4){0.f, 0.f, 0.f, 0.f};

        short8 areg[2], breg[2];
#pragma unroll
        for (int p = 0; p < 2; ++p) {
            int c = tid + (p << 9);
            int row = c >> 3, col8 = (c & 7) << 3;
            areg[p] = *(const short8*)(xh + (size_t)(m0 + row) * K + col8);
            breg[p] = *(const short8*)(Wqt + (size_t)(n0 + row) * K + col8);
        }

        for (int k0 = 0; k0 < K; k0 += 64) {
            __syncthreads();
#pragma unroll
            for (int p = 0; p < 2; ++p) {
                int c = tid + (p << 9);
                int row = c >> 3, col8 = (c & 7) << 3;
                *(short8*)&As[row * 72 + col8] = areg[p];
                *(short8*)&Bs[row * 72 + col8] = breg[p];
            }
            __syncthreads();
            if (k0 + 64 < K) {
#pragma unroll
                for (int p = 0; p < 2; ++p) {
                    int c = tid + (p << 9);
                    int row = c >> 3, col8 = (c & 7) << 3;
                    areg[p] = *(const short8*)(xh + (size_t)(m0 + row) * K + k0 + 64 + col8);
                    breg[p] = *(const short8*)(Wqt + (size_t)(n0 + row) * K + k0 + 64 + col8);
                }
            }
#pragma unroll
            for (int ch = 0; ch < 2; ++ch) {
                short8 af[4], bf[2];
#pragma unroll
                for (int mt = 0; mt < 4; ++mt)
                    af[mt] = *(const short8*)&As[(mh + mt * 16 + ln) * 72 + ch * 32 + quad * 8];
#pragma unroll
                for (int nt = 0; nt < 2; ++nt)
                    bf[nt] = *(const short8*)&Bs[(nh + nt * 16 + ln) * 72 + ch * 32 + quad * 8];
#pragma unroll
                for (int mt = 0; mt < 4; ++mt)
#pragma unroll
                    for (int nt = 0; nt < 2; ++nt)
                        acc[mt][nt] = __builtin_amdgcn_mfma_f32_16x16x32_bf16(
                            af[mt], bf[nt], acc[mt][nt], 0, 0, 0);
            }
        }

#pragma unroll
        for (int mt = 0; mt < 4; ++mt)
#pragma unroll
            for (int nt = 0; nt < 2; ++nt) {
                int n = n0 + nh + nt * 16 + ln;
                int mb = m0 + mh + mt * 16 + quad * 4;
                int b = mb >> 11, s0 = mb & (SEQ - 1);
                int d = n & 63;
                if (n < DMODEL) {           // Q, pre-scaled incl. log2(e)
                    int h = n >> 6;
                    unsigned short* qp_ =
                        qb + ((size_t)(b * NH + h) * SEQ + s0) * DHEAD + d;
#pragma unroll
                    for (int r = 0; r < 4; ++r)
                        qp_[(size_t)r * DHEAD] = f2bf(acc[mt][nt][r] * 0.18033688f);
                } else {                    // V: row-major + transposed
                    int h = (n >> 6) - NH;
                    unsigned short* vp_ =
                        vb + ((size_t)(b * NH + h) * SEQ + s0) * DHEAD + d;
                    short4v tv;
#pragma unroll
                    for (int r = 0; r < 4; ++r) {
                        unsigned short bv = f2bf(acc[mt][nt][r]);
                        vp_[(size_t)r * DHEAD] = bv;
                        tv[r] = (short)bv;
                    }
                    *(short4v*)(vtout + ((size_t)(b * NH + h) * DHEAD + d) * SEQ + s0) = tv;
                }
            }
    } else {
        // ------- kproj path (compensated, 128x128, BK=32, M2xN4) -------
        unsigned short* Ah = smem;            // [128][40] each
        unsigned short* Al = smem + 5120;
        unsigned short* Bh = smem + 10240;
        unsigned short* Bl = smem + 15360;
        const int sb = blk - 512;
        const int xcd = sb & 7, t2 = sb >> 3;        // t2 = (m/8) + 4*n
        const int m0 = ((t2 & 3) * 8 + xcd) * 128;   // m in [0,32)
        const int n0 = (t2 >> 2) * 128;              // n in [0,8)
        const int mh = (wave >> 1) << 5;      // 4 m-groups x 32 rows
        const int nh = (wave & 1) << 6;       // 2 n-groups x 64 cols

        f32x4 acc[2][4];
#pragma unroll
        for (int i = 0; i < 2; ++i)
#pragma unroll
            for (int j = 0; j < 4; ++j) acc[i][j] = (f32x4){0.f, 0.f, 0.f, 0.f};

        const int krow = tid >> 2, kcol8 = (tid & 3) << 3;   // 128 x 32
        short8 ahreg, alreg, bhreg, blreg;
        {
            size_t ga = (size_t)(m0 + krow) * K + kcol8;
            size_t gb = (size_t)(n0 + krow) * K + kcol8;
            ahreg = *(const short8*)(xh + ga);
            alreg = *(const short8*)(xl + ga);
            bhreg = *(const short8*)(Wkh + gb);
            blreg = *(const short8*)(Wkl + gb);
        }

        for (int k0 = 0; k0 < K; k0 += 32) {
            __syncthreads();
            *(short8*)&Ah[krow * 40 + kcol8] = ahreg;
            *(short8*)&Al[krow * 40 + kcol8] = alreg;
            *(short8*)&Bh[krow * 40 + kcol8] = bhreg;
            *(short8*)&Bl[krow * 40 + kcol8] = blreg;
            __syncthreads();
            if (k0 + 32 < K) {
                size_t ga = (size_t)(m0 + krow) * K + k0 + 32 + kcol8;
                size_t gb = (size_t)(n0 + krow) * K + k0 + 32 + kcol8;
                ahreg = *(const short8*)(xh + ga);
                alreg = *(const short8*)(xl + ga);
                bhreg = *(const short8*)(Wkh + gb);
                blreg = *(const short8*)(Wkl + gb);
            }
            short8 afh[2], afl[2];
#pragma unroll
            for (int mt = 0; mt < 2; ++mt) {
                afh[mt] = *(const short8*)&Ah[(mh + mt * 16 + ln) * 40 + quad * 8];
                afl[mt] = *(const short8*)&Al[(mh + mt * 16 + ln) * 40 + quad * 8];
            }
#pragma unroll
            for (int nt = 0; nt < 4; ++nt) {
                short8 bfh = *(const short8*)&Bh[(nh + nt * 16 + ln) * 40 + quad * 8];
                short8 bfl = *(const short8*)&Bl[(nh + nt * 16 + ln) * 40 + quad * 8];
#pragma unroll
                for (int mt = 0; mt < 2; ++mt) {
                    acc[mt][nt] = __builtin_amdgcn_mfma_f32_16x16x32_bf16(afh[mt], bfh, acc[mt][nt], 0, 0, 0);
                    acc[mt][nt] = __builtin_amdgcn_mfma_f32_16x16x32_bf16(afh[mt], bfl, acc[mt][nt], 0, 0, 0);
                    acc[mt][nt] = __builtin_amdgcn_mfma_f32_16x16x32_bf16(afl[mt], bfh, acc[mt][nt], 0, 0, 0);
                }
            }
        }

        const int h = (n0 + nh) >> 6;
#pragma unroll
        for (int mt = 0; mt < 2; ++mt)
#pragma unroll
            for (int r = 0; r < 4; ++r) {
                int m = m0 + mh + mt * 16 + quad * 4 + r;
                int b = m >> 11, s = m & (SEQ - 1);
                size_t rowbase = ((size_t)(b * NH + h) * SEQ + s) * DHEAD;
#pragma unroll
                for (int nt = 0; nt < 4; ++nt)
                    kout[rowbase + nt * 16 + ln] = f2bf(acc[mt][nt][r]);
                float s2 = acc[mt][0][r] * acc[mt][0][r] + acc[mt][1][r] * acc[mt][1][r] +
                           acc[mt][2][r] * acc[mt][2][r] + acc[mt][3][r] * acc[mt][3][r];
#pragma unroll
                for (int off = 1; off <= 8; off <<= 1)
                    s2 += __shfl_xor(s2, off);
                if (ln == 0)
                    norms2[(size_t)(b * NH + h) * SEQ + s] = s2;
            }
    }
}

// ---------------------------------------------------------------------------
// topk + gather fused, 1024 threads (2 CE/thread over 66 bitonic stages).
// ---------------------------------------------------------------------------
__global__ __launch_bounds__(1024)
void topk_gather_k(const float* __restrict__ norms2,
                   const unsigned short* __restrict__ k,
                   const unsigned short* __restrict__ v,
                   unsigned short* __restrict__ gk,
                   unsigned short* __restrict__ gvt)
{
    __shared__ unsigned long long keys[SEQ];
    __shared__ int tix[NGPAD];
    __shared__ __align__(16) unsigned short T[64][72];
    const int bh = blockIdx.x;
    const int tid = threadIdx.x;
    const float* nb = norms2 + (size_t)bh * SEQ;
    const size_t base = (size_t)bh * SEQ * DHEAD;

    for (int i = tid; i < SEQ; i += 1024) {
        float nrm = sqrtf(nb[i]);
        keys[i] = ((unsigned long long)__float_as_uint(nrm) << 32) |
                  (unsigned int)(0xFFFFFFFFu - (unsigned int)i);
    }
    __syncthreads();
    for (int kk = 2; kk <= SEQ; kk <<= 1) {
        for (int j = kk >> 1; j > 0; j >>= 1) {
            for (int i = tid; i < SEQ; i += 1024) {
                int ixj = i ^ j;
                if (ixj > i) {
                    unsigned long long a = keys[i], b = keys[ixj];
                    bool up = ((i & kk) == 0);
                    if ((a > b) == up) { keys[i] = b; keys[ixj] = a; }
                }
            }
            __syncthreads();
        }
    }
    if (tid < NGPAD) {
        tix[tid] = (tid < NG)
            ? (int)(0xFFFFFFFFu - (unsigned int)(keys[SEQ - 1 - tid] & 0xFFFFFFFFu))
            : 0;
    }
    __syncthreads();

    for (int t = 0; t < NGPAD / 64; ++t) {
        {
            int row = tid >> 4, col4 = (tid & 15) << 2;   // 64 rows x 64 cols
            int g = t * 64 + row;
            short4v kv = (short4v)0, vv = (short4v)0;
            if (g < NG) {
                int sidx = tix[g];
                kv = *(const short4v*)(k + base + (size_t)sidx * DHEAD + col4);
                vv = *(const short4v*)(v + base + (size_t)sidx * DHEAD + col4);
            }
            *(short4v*)(gk + ((size_t)bh * NGPAD + g) * DHEAD + col4) = kv;
            *(short4v*)&T[row][col4] = vv;
        }
        __syncthreads();
        {
            int d = tid >> 4, k4 = (tid & 15) << 2;
            short4v o;
#pragma unroll
            for (int i = 0; i < 4; ++i) o[i] = (short)T[k4 + i][d];
            *(short4v*)(gvt + ((size_t)bh * DHEAD + d) * NGPAD + t * 64 + k4) = o;
        }
        __syncthreads();
    }
}

// ---------------------------------------------------------------------------
// Fused attention (r19): 256 thr, 4 waves x 32 q-rows, swapped QK^T, P in
// registers as mfma32 A-frags via phi K-row permutation; K/V double-
// buffered; row-sums via ones-MFMA; Wg gate direct from global.
// ---------------------------------------------------------------------------
__global__ __launch_bounds__(256, 2)
void attn_fused_k(const unsigned short* __restrict__ qb,
                  const unsigned short* __restrict__ kb,
                  const unsigned short* __restrict__ vt,
                  const unsigned short* __restrict__ gk,
                  const unsigned short* __restrict__ gvt,
                  const unsigned short* __restrict__ Wgt,
                  const float* __restrict__ gamma,
                  const float* __restrict__ beta,
                  const float* __restrict__ bg,
                  unsigned short* __restrict__ fused)
{
    // smem layout (shorts): [0,9216) Ks[2][64][72]  (= Ps[128][72] alias)
    //                       [9216,18432) Vt[2][64][72]
    __shared__ __align__(16) unsigned short smem[18432];
    unsigned short* const KsB = smem;
    unsigned short* const VtB = smem + 9216;
    unsigned short (*Ps)[72]  = (unsigned short (*)[72])smem;

    const int flat = blockIdx.x;
    const int bh = ((flat >> 7) << 3) | (flat & 7);   // flat%8 == bh%8 (XCD)
    const int q0 = ((flat >> 3) & 15) * 128;
    const int tid = threadIdx.x;
    const int lane = tid & 63, wave = tid >> 6;       // 4 waves
    const int quad = lane >> 4, ln = lane & 15;
    const size_t base = (size_t)bh * SEQ * DHEAD;
    const unsigned short* gkb = gk + (size_t)bh * NGPAD * DHEAD;
    const unsigned short* gvb = gvt + (size_t)bh * DHEAD * NGPAD;

    short8 qf[2][2];
#pragma unroll
    for (int mt = 0; mt < 2; ++mt) {
        const unsigned short* qp = qb + base + (size_t)(q0 + wave * 32 + mt * 16 + ln) * DHEAD;
        qf[mt][0] = *(const short8*)(qp + quad * 8);
        qf[mt][1] = *(const short8*)(qp + 32 + quad * 8);
    }

    // ones / last-tile-mask B-frags for row-sum MFMAs
    short8 onesv, maskv;
#pragma unroll
    for (int j = 0; j < 8; ++j) {
        onesv[j] = (short)0x3F80;                              // bf16 1.0
        maskv[j] = (short)((quad * 8 + j) < 12 ? 0x3F80 : 0);  // NG-192=12
    }

    f32x4 O[2][4], Og[2][4], lsacc[2], lgacc[2];
#pragma unroll
    for (int mt = 0; mt < 2; ++mt) {
#pragma unroll
        for (int nt = 0; nt < 4; ++nt) {
            O[mt][nt] = (f32x4){0.f, 0.f, 0.f, 0.f};
            Og[mt][nt] = (f32x4){0.f, 0.f, 0.f, 0.f};
        }
        lsacc[mt] = (f32x4){0.f, 0.f, 0.f, 0.f};
        lgacc[mt] = (f32x4){0.f, 0.f, 0.f, 0.f};
    }

    short8 kreg[2], vreg[2];
    int srow[2], scol8[2], psrow[2];
#pragma unroll
    for (int p = 0; p < 2; ++p) {
        int idx = tid + (p << 8);
        srow[p] = idx >> 3;
        scol8[p] = (idx & 7) << 3;
        // phi: [b5 | b3 b2 | b4 | b1 b0]  (K-row permutation, verified r14)
        psrow[p] = (srow[p] & 0x20) | ((srow[p] & 0x0C) << 1) |
                   ((srow[p] & 0x10) >> 2) | (srow[p] & 3);
    }

    auto loadT = [&](int i) {
#pragma unroll
        for (int p = 0; p < 2; ++p) {
            if (i < 32) {
                kreg[p] = *(const short8*)(kb + base + (size_t)(i * 64 + psrow[p]) * DHEAD + scol8[p]);
                vreg[p] = *(const short8*)(vt + base + (size_t)srow[p] * SEQ + i * 64 + scol8[p]);
            } else {
                int g = i - 32;
                kreg[p] = *(const short8*)(gkb + (size_t)(g * 64 + psrow[p]) * DHEAD + scol8[p]);
                vreg[p] = *(const short8*)(gvb + (size_t)srow[p] * NGPAD + g * 64 + scol8[p]);
            }
        }
    };
    auto storeT = [&](int buf) {
        unsigned short* kd = KsB + buf * 4608;
        unsigned short* vd = VtB + buf * 4608;
#pragma unroll
        for (int p = 0; p < 2; ++p) {
            *(short8*)&kd[srow[p] * 72 + scol8[p]] = kreg[p];
            *(short8*)&vd[srow[p] * 72 + scol8[p]] = vreg[p];
        }
    };

    loadT(0);
    storeT(0);
    loadT(1);
    __syncthreads();

    // ---- local: 32 tiles ----
    for (int t = 0; t < 32; ++t) {
        const int cur = t & 1;
        const unsigned short* Kc = KsB + cur * 4608;
        const unsigned short* Vc = VtB + cur * 4608;

        // swapped QK^T: lane holds S^T[k_phys = phi(nt*16+quad*4+r)][q=ln]
        f32x4 s[2][4];
#pragma unroll
        for (int mt = 0; mt < 2; ++mt)
#pragma unroll
            for (int nt = 0; nt < 4; ++nt) s[mt][nt] = (f32x4){0.f, 0.f, 0.f, 0.f};
        __builtin_amdgcn_s_setprio(1);
#pragma unroll
        for (int nt = 0; nt < 4; ++nt) {
            short8 kf0 = *(const short8*)&Kc[(nt * 16 + ln) * 72 + quad * 8];
            short8 kf1 = *(const short8*)&Kc[(nt * 16 + ln) * 72 + 32 + quad * 8];
#pragma unroll
            for (int mt = 0; mt < 2; ++mt) {
                s[mt][nt] = __builtin_amdgcn_mfma_f32_16x16x32_bf16(kf0, qf[mt][0], s[mt][nt], 0, 0, 0);
                s[mt][nt] = __builtin_amdgcn_mfma_f32_16x16x32_bf16(kf1, qf[mt][1], s[mt][nt], 0, 0, 0);
            }
        }
        __builtin_amdgcn_s_setprio(0);

        // exp + pack into mfma32 A-frags: pf8[mt][c] = k_phys c*32+quad*8+[0..7]
        short8 pf8[2][2];
#pragma unroll
        for (int mt = 0; mt < 2; ++mt)
#pragma unroll
            for (int nt = 0; nt < 4; ++nt)
#pragma unroll
                for (int r = 0; r < 4; ++r) {
                    unsigned int u = __float_as_uint(__builtin_amdgcn_exp2f(s[mt][nt][r]));
                    pf8[mt][nt >> 1][((nt & 1) << 2) | r] = (short)(u >> 16);
                }

        // PV + row-sum: full-rate mfma32, P from registers
        __builtin_amdgcn_s_setprio(1);
#pragma unroll
        for (int dt = 0; dt < 4; ++dt)
#pragma unroll
            for (int c = 0; c < 2; ++c) {
                short8 vf = *(const short8*)&Vc[(dt * 16 + ln) * 72 + c * 32 + quad * 8];
#pragma unroll
                for (int mt = 0; mt < 2; ++mt)
                    O[mt][dt] = __builtin_amdgcn_mfma_f32_16x16x32_bf16(
                        pf8[mt][c], vf, O[mt][dt], 0, 0, 0);
            }
#pragma unroll
        for (int c = 0; c < 2; ++c)
#pragma unroll
            for (int mt = 0; mt < 2; ++mt)
                lsacc[mt] = __builtin_amdgcn_mfma_f32_16x16x32_bf16(
                    pf8[mt][c], onesv, lsacc[mt], 0, 0, 0);
        __builtin_amdgcn_s_setprio(0);

        storeT(cur ^ 1);            // tile t+1 -> other buffer
        if (t + 2 <= 35) loadT(t + 2);
        __syncthreads();
    }

    // ---- global: 4 gathered tiles (padded rows: K=0 -> P=1, V=0; mask
    //      excludes them from lgacc; tiles 0-2 fully valid) ----
    for (int tg = 0; tg < 4; ++tg) {
        const int t = 32 + tg;
        const int cur = t & 1;
        const unsigned short* Kc = KsB + cur * 4608;
        const unsigned short* Vc = VtB + cur * 4608;

        f32x4 s[2][4];
#pragma unroll
        for (int mt = 0; mt < 2; ++mt)
#pragma unroll
            for (int nt = 0; nt < 4; ++nt) s[mt][nt] = (f32x4){0.f, 0.f, 0.f, 0.f};
        __builtin_amdgcn_s_setprio(1);
#pragma unroll
        for (int nt = 0; nt < 4; ++nt) {
            short8 kf0 = *(const short8*)&Kc[(nt * 16 + ln) * 72 + quad * 8];
            short8 kf1 = *(const short8*)&Kc[(nt * 16 + ln) * 72 + 32 + quad * 8];
#pragma unroll
            for (int mt = 0; mt < 2; ++mt) {
                s[mt][nt] = __builtin_amdgcn_mfma_f32_16x16x32_bf16(kf0, qf[mt][0], s[mt][nt], 0, 0, 0);
                s[mt][nt] = __builtin_amdgcn_mfma_f32_16x16x32_bf16(kf1, qf[mt][1], s[mt][nt], 0, 0, 0);
            }
        }
        __builtin_amdgcn_s_setprio(0);

        short8 pf8[2][2];
#pragma unroll
        for (int mt = 0; mt < 2; ++mt)
#pragma unroll
            for (int nt = 0; nt < 4; ++nt)
#pragma unroll
                for (int r = 0; r < 4; ++r) {
                    unsigned int u = __float_as_uint(__builtin_amdgcn_exp2f(s[mt][nt][r]));
                    pf8[mt][nt >> 1][((nt & 1) << 2) | r] = (short)(u >> 16);
                }

        __builtin_amdgcn_s_setprio(1);
#pragma unroll
        for (int dt = 0; dt < 4; ++dt)
#pragma unroll
            for (int c = 0; c < 2; ++c) {
                short8 vf = *(const short8*)&Vc[(dt * 16 + ln) * 72 + c * 32 + quad * 8];
#pragma unroll
                for (int mt = 0; mt < 2; ++mt)
                    Og[mt][dt] = __builtin_amdgcn_mfma_f32_16x16x32_bf16(
                        pf8[mt][c], vf, Og[mt][dt], 0, 0, 0);
            }
        if (tg < 3) {
#pragma unroll
            for (int c = 0; c < 2; ++c)
#pragma unroll
                for (int mt = 0; mt < 2; ++mt)
                    lgacc[mt] = __builtin_amdgcn_mfma_f32_16x16x32_bf16(
                        pf8[mt][c], onesv, lgacc[mt], 0, 0, 0);
        } else {
            // last tile: only k_phys < 12 valid (c=0 chunk), via maskv
#pragma unroll
            for (int mt = 0; mt < 2; ++mt)
                lgacc[mt] = __builtin_amdgcn_mfma_f32_16x16x32_bf16(
                    pf8[mt][0], maskv, lgacc[mt], 0, 0, 0);
        }
        __builtin_amdgcn_s_setprio(0);

        if (t < 35) storeT(cur ^ 1);
        if (t + 2 <= 35) loadT(t + 2);
        __syncthreads();            // last iter: protects Ps alias in epilogue
    }

    // ---- row sums already in O layout (q = quad*4+r) ----
    float invl[2][4], invg[2][4];
#pragma unroll
    for (int mt = 0; mt < 2; ++mt)
#pragma unroll
        for (int r = 0; r < 4; ++r) {
            invl[mt][r] = 1.f / lsacc[mt][r];
            invg[mt][r] = 1.f / lgacc[mt][r];
        }

    // ---- layernorm(global) ----
    float xs[2][4][4];
#pragma unroll
    for (int mt = 0; mt < 2; ++mt)
#pragma unroll
        for (int r = 0; r < 4; ++r) {
            float inv = invg[mt][r];
#pragma unroll
            for (int nt = 0; nt < 4; ++nt) xs[mt][nt][r] = Og[mt][nt][r] * inv;
        }
    float mu[2][4], rsd[2][4];
#pragma unroll
    for (int mt = 0; mt < 2; ++mt)
#pragma unroll
        for (int r = 0; r < 4; ++r) {
            float sm = xs[mt][0][r] + xs[mt][1][r] + xs[mt][2][r] + xs[mt][3][r];
#pragma unroll
            for (int off = 1; off <= 8; off <<= 1) sm += __shfl_xor(sm, off);
            mu[mt][r] = sm * (1.f / 64.f);
        }
#pragma unroll
    for (int mt = 0; mt < 2; ++mt)
#pragma unroll
        for (int r = 0; r < 4; ++r) {
            float sv = 0.f;
#pragma unroll
            for (int nt = 0; nt < 4; ++nt) {
                float d = xs[mt][nt][r] - mu[mt][r];
                sv += d * d;
            }
#pragma unroll
            for (int off = 1; off <= 8; off <<= 1) sv += __shfl_xor(sv, off);
            rsd[mt][r] = rsqrtf(sv * (1.f / 64.f) + LNEPS);
        }
#pragma unroll
    for (int nt = 0; nt < 4; ++nt) {
        float g = gamma[nt * 16 + ln], bb = beta[nt * 16 + ln];
#pragma unroll
        for (int mt = 0; mt < 2; ++mt)
#pragma unroll
            for (int r = 0; r < 4; ++r)
                xs[mt][nt][r] = (xs[mt][nt][r] - mu[mt][r]) * rsd[mt][r] * g + bb;
    }

    // ---- gate via MFMA (Ps alias; intra-wave rows, no barrier; Wg from
    //      global Wgt - r14-verified path) ----
    float lf[2][4][4];
#pragma unroll
    for (int mt = 0; mt < 2; ++mt)
#pragma unroll
        for (int nt = 0; nt < 4; ++nt)
#pragma unroll
            for (int r = 0; r < 4; ++r) {
                lf[mt][nt][r] = O[mt][nt][r] * invl[mt][r];
                Ps[wave * 32 + mt * 16 + quad * 4 + r][nt * 16 + ln] = f2bf(lf[mt][nt][r]);
            }
    f32x4 gacc[2][4];
#pragma unroll
    for (int ng = 0; ng < 4; ++ng) {
        float bgv = bg[ng * 16 + ln];
#pragma unroll
        for (int mt = 0; mt < 2; ++mt)
            gacc[mt][ng] = (f32x4){bgv, bgv, bgv, bgv};
    }
#pragma unroll
    for (int ch = 0; ch < 2; ++ch) {
        short8 af[2];
#pragma unroll
        for (int mt = 0; mt < 2; ++mt)
            af[mt] = *(const short8*)&Ps[wave * 32 + mt * 16 + ln][ch * 32 + quad * 8];
#pragma unroll
        for (int ng = 0; ng < 4; ++ng) {
            short8 bf = *(const short8*)(Wgt + (size_t)(ng * 16 + ln) * 128 + ch * 32 + quad * 8);
#pragma unroll
            for (int mt = 0; mt < 2; ++mt)
                gacc[mt][ng] = __builtin_amdgcn_mfma_f32_16x16x32_bf16(af[mt], bf, gacc[mt][ng], 0, 0, 0);
        }
    }
#pragma unroll
    for (int mt = 0; mt < 2; ++mt)
#pragma unroll
        for (int nt = 0; nt < 4; ++nt)
#pragma unroll
            for (int r = 0; r < 4; ++r)
                Ps[wave * 32 + mt * 16 + quad * 4 + r][nt * 16 + ln] = f2bf(xs[mt][nt][r]);
#pragma unroll
    for (int ch = 0; ch < 2; ++ch) {
        short8 af[2];
#pragma unroll
        for (int mt = 0; mt < 2; ++mt)
            af[mt] = *(const short8*)&Ps[wave * 32 + mt * 16 + ln][ch * 32 + quad * 8];
#pragma unroll
        for (int ng = 0; ng < 4; ++ng) {
            short8 bf = *(const short8*)(Wgt + (size_t)(ng * 16 + ln) * 128 + 64 + ch * 32 + quad * 8);
#pragma unroll
            for (int mt = 0; mt < 2; ++mt)
                gacc[mt][ng] = __builtin_amdgcn_mfma_f32_16x16x32_bf16(af[mt], bf, gacc[mt][ng], 0, 0, 0);
        }
    }

    // ---- fuse + store ----
    const int b = bh >> 4, h = bh & 15;
#pragma unroll
    for (int mt = 0; mt < 2; ++mt)
#pragma unroll
        for (int ng = 0; ng < 4; ++ng)
#pragma unroll
            for (int r = 0; r < 4; ++r) {
                float gt = 1.f / (1.f + __expf(-gacc[mt][ng][r]));
                float f = gt * lf[mt][ng][r] + (1.f - gt) * xs[mt][ng][r];
                int s = q0 + wave * 32 + mt * 16 + quad * 4 + r;
                fused[((size_t)(b * SEQ + s)) * DMODEL + h * DHEAD + ng * 16 + ln] = f2bf(f);
            }
}

// ---------------------------------------------------------------------------
extern "C" void kernel_launch(void* const* d_in, const int* in_sizes, int n_in,
                              void* d_out, int out_size, void* d_ws, size_t ws_size,
                              hipStream_t stream)
{
    (void)in_sizes; (void)n_in; (void)out_size; (void)ws_size;
    const float* x    = (const float*)d_in[0];
    const float* Wq   = (const float*)d_in[1];
    const float* Wk   = (const float*)d_in[2];
    const float* Wv   = (const float*)d_in[3];
    const float* Wo   = (const float*)d_in[4];
    const float* bo   = (const float*)d_in[5];
    const float* ln_g = (const float*)d_in[6];
    const float* ln_b = (const float*)d_in[7];
    const float* Wg   = (const float*)d_in[8];
    const float* bg   = (const float*)d_in[9];

    char* w = (char*)d_ws;
    const size_t MB = 1024ull * 1024ull;
    unsigned short* kb16  = (unsigned short*)(w);
    unsigned short* qb16  = (unsigned short*)(w + 8 * MB);
    unsigned short* vb16  = (unsigned short*)(w + 16 * MB);
    unsigned short* vt16  = (unsigned short*)(w + 24 * MB);
    unsigned short* xh    = (unsigned short*)(w + 32 * MB);
    unsigned short* xl    = (unsigned short*)(w + 40 * MB);
    unsigned short* Wqt   = (unsigned short*)(w + 48 * MB);
    unsigned short* Wvt   = (unsigned short*)(w + 50 * MB);   // contiguous after Wqt
    unsigned short* Wot   = (unsigned short*)(w + 52 * MB);
    unsigned short* Wkh   = (unsigned short*)(w + 54 * MB);
    unsigned short* Wkl   = (unsigned short*)(w + 56 * MB);
    unsigned short* Wgt   = (unsigned short*)(w + 58 * MB);
    float*          norms2= (float*)(w + 59 * MB);
    unsigned short* gk16  = (unsigned short*)(w + 60 * MB);
    unsigned short* gvt16 = (unsigned short*)(w + 61 * MB);
    unsigned short* fusedb = xh;   // xh dead after projections
    (void)Wvt;

    const int M = 4096, N = 1024, K = 1024;

    prep_k<<<3073, 256, 0, stream>>>(x, Wq, Wv, Wo, Wk, Wg,
                                     xh, xl, Wqt, Wvt, Wot, Wkh, Wkl, Wgt);

    proj_qvk_k<<<768, 512, 0, stream>>>(xh, xl, Wqt, Wkh, Wkl,
                                        qb16, vb16, vt16, kb16, norms2);

    topk_gather_k<<<BHT, 1024, 0, stream>>>(norms2, kb16, vb16, gk16, gvt16);

    attn_fused_k<<<512, 256, 0, stream>>>(qb16, kb16, vt16, gk16, gvt16, Wgt,
                                          ln_g, ln_b, bg, fusedb);

    gemm_bf16_k<<<256, 512, 0, stream>>>(fusedb, Wot, bo, (float*)d_out,
                                         M, N, K);
}